// Round 4
// baseline (285.004 us; speedup 1.0000x reference)
//
#include <hip/hip_runtime.h>

// DfOpCoefLoop: deep-filtering over first 96 freq bins, 5-tap complex FIR in
// time (lookahead 2), alpha-blended with dry spec; remaining bins copied.
//
// spec  : (B=32, 1, T=1000, F=481, 2) f32   = 123.1 MB
// coefs : (B=32, T=1000, ORDER=5, DF=96, 2) = 122.9 MB
// alpha : (B=32, T=1000, 1) f32
// out   : same shape as spec                = 123.1 MB
//
// Memory-bound: ~369 MB mandatory traffic -> ~59 us floor @6.3 TB/s.

typedef float f2 __attribute__((ext_vector_type(2)));   // nt-builtin-friendly float2

#define ORDER 5
#define TPAD  2        // ORDER - LOOKAHEAD - 1
#define LOOKAHEAD 2
#define NDF   96
#define NF    481
#define TT    1000
#define BB    32
#define NROWS (BB * TT)

__global__ __launch_bounds__(256) void df_kernel(
    const float* __restrict__ spec,
    const float* __restrict__ coefs,
    const float* __restrict__ alpha,
    float* __restrict__ out)
{
    // XCD-chunked swizzle: 32000 blocks / 8 XCDs -> each XCD gets a contiguous
    // 4000-row range, so the r-2..r+2 DF tap reuse hits its own L2.
    // Bijective since NROWS % 8 == 0.
    const int bid = blockIdx.x;
    const int row = (bid & 7) * (NROWS / 8) + (bid >> 3);
    const int t   = row % TT;              // block-uniform
    const int tid = threadIdx.x;

    const f2* __restrict__ srow = (const f2*)(spec  + (size_t)row * (NF * 2));
    f2* __restrict__       orow = (f2*)      (out   + (size_t)row * (NF * 2));
    const f2* __restrict__ crow = (const f2*)(coefs + (size_t)row * (ORDER * NDF * 2));

    const float a   = alpha[row];          // uniform scalar
    const float oma = 1.0f - a;
    const bool interior = (t >= TPAD) & (t < TT - LOOKAHEAD);   // block-uniform

    // Work unit B (u = tid+256): ALWAYS a tail copy (256 > NDF). Issue its
    // load first so its HBM latency overlaps the DF compute below.
    const int uB = tid + 256;
    const bool hasB = (uB < NF);
    f2 vB;
    if (hasB) vB = __builtin_nontemporal_load(&srow[uB]);

    // Work unit A (u = tid): DF bin if tid<96, else tail copy.
    if (tid < NDF) {
        const int u = tid;
        float accre, accim;
        f2 s;                                     // dry (center-tap) value
        if (interior) {
            // fast path (99.6% of blocks): all 5 taps valid, branch-free —
            // all 10 loads issue back-to-back for max memory-level parallelism.
            f2 w0 = ((const f2*)(spec + (size_t)(row - 2) * (NF * 2)))[u];
            f2 w1 = ((const f2*)(spec + (size_t)(row - 1) * (NF * 2)))[u];
            f2 w2 = srow[u];
            f2 w3 = ((const f2*)(spec + (size_t)(row + 1) * (NF * 2)))[u];
            f2 w4 = ((const f2*)(spec + (size_t)(row + 2) * (NF * 2)))[u];
            f2 c0 = __builtin_nontemporal_load(&crow[0 * NDF + u]);
            f2 c1 = __builtin_nontemporal_load(&crow[1 * NDF + u]);
            f2 c2 = __builtin_nontemporal_load(&crow[2 * NDF + u]);
            f2 c3 = __builtin_nontemporal_load(&crow[3 * NDF + u]);
            f2 c4 = __builtin_nontemporal_load(&crow[4 * NDF + u]);
            accre  = w0.x * c0.x - w0.y * c0.y;
            accim  = w0.y * c0.x + w0.x * c0.y;
            accre += w1.x * c1.x - w1.y * c1.y;
            accim += w1.y * c1.x + w1.x * c1.y;
            accre += w2.x * c2.x - w2.y * c2.y;
            accim += w2.y * c2.x + w2.x * c2.y;
            accre += w3.x * c3.x - w3.y * c3.y;
            accim += w3.y * c3.x + w3.x * c3.y;
            accre += w4.x * c4.x - w4.y * c4.y;
            accim += w4.y * c4.x + w4.x * c4.y;
            s = w2;
        } else {
            // boundary path (t in {0,1,998,999}): skip taps outside [0, T)
            accre = 0.0f; accim = 0.0f;
            s = srow[u];
#pragma unroll
            for (int i = 0; i < ORDER; ++i) {
                const int ts = t + i - TPAD;      // block-uniform condition
                if (ts >= 0 && ts < TT) {
                    const f2 w = (i == TPAD)
                        ? s
                        : ((const f2*)(spec + (size_t)(row + i - TPAD) * (NF * 2)))[u];
                    const f2 c = __builtin_nontemporal_load(&crow[i * NDF + u]);
                    accre += w.x * c.x - w.y * c.y;
                    accim += w.y * c.x + w.x * c.y;
                }
            }
        }
        f2 o;
        o.x = accre * a + s.x * oma;
        o.y = accim * a + s.y * oma;
        __builtin_nontemporal_store(o, &orow[u]);
    } else {
        const int u = tid;                        // 96..255: always valid tail bin
        const f2 v = __builtin_nontemporal_load(&srow[u]);
        __builtin_nontemporal_store(v, &orow[u]);
    }

    if (hasB) __builtin_nontemporal_store(vB, &orow[uB]);
}

extern "C" void kernel_launch(void* const* d_in, const int* in_sizes, int n_in,
                              void* d_out, int out_size, void* d_ws, size_t ws_size,
                              hipStream_t stream) {
    const float* spec  = (const float*)d_in[0];
    const float* coefs = (const float*)d_in[1];
    const float* alpha = (const float*)d_in[2];
    float* out = (float*)d_out;

    dim3 grid(NROWS);   // one block per (b,t) row
    dim3 block(256);
    df_kernel<<<grid, block, 0, stream>>>(spec, coefs, alpha, out);
}